// Round 1
// baseline (338.048 us; speedup 1.0000x reference)
//
#include <hip/hip_runtime.h>
#include <hip/hip_bf16.h>

#define B_    8
#define N_    2048
#define FIN_  256
#define FOUT_ 128

// ---------- dtype-agnostic load (flag: 1 = bf16 inputs, 0 = fp32) ----------
__device__ __forceinline__ float ldin(const void* p, long idx, int isbf) {
  if (isbf) {
    unsigned short u = ((const unsigned short*)p)[idx];
    return __uint_as_float(((unsigned int)u) << 16);
  } else {
    return ((const float*)p)[idx];
  }
}

__device__ __forceinline__ unsigned short f2bf(float f) {
  unsigned int u = __float_as_uint(f);
  u += 0x7FFFu + ((u >> 16) & 1u);   // RNE
  return (unsigned short)(u >> 16);
}

// ---------- kernel 0: detect whether inputs are bf16 or fp32 ----------
// bf16 N(0,1) data: ~100% of uint16s have exponent field in [110,145].
// fp32 data: odd uint16s are high halves (plausible), even are random mantissa
// bits (~14% plausible) -> total ~57%. Threshold at 90%.
__global__ void k_detect(const void* x, int* flag) {
  __shared__ int cnt[256];
  const unsigned short* u = (const unsigned short*)x;
  int c = 0;
  for (int i = threadIdx.x; i < 16384; i += 256) {
    unsigned short v = u[i];
    int e = (v >> 7) & 0xFF;
    if ((e >= 110 && e <= 145) || (v & 0x7FFF) == 0) c++;
  }
  cnt[threadIdx.x] = c;
  __syncthreads();
  for (int s = 128; s > 0; s >>= 1) {
    if (threadIdx.x < s) cnt[threadIdx.x] += cnt[threadIdx.x + s];
    __syncthreads();
  }
  if (threadIdx.x == 0) *flag = (cnt[0] > 14745) ? 1 : 0;  // 0.9 * 16384
}

// ---------- kernel 1: h = x @ W, f_src = h@a[:F], f_dst = h@a[F:] ----------
// grid = B*N/16 blocks, 128 threads (one per output feature).
__global__ __launch_bounds__(128)
void k_h(const void* __restrict__ x, const void* __restrict__ W,
         const void* __restrict__ a, const int* __restrict__ flag,
         float* __restrict__ h, float* __restrict__ fsrc, float* __restrict__ fdst) {
  const int isbf = *flag;
  const int j    = threadIdx.x;           // output feature 0..127
  const int row0 = blockIdx.x * 16;       // global row within [B*N]

  __shared__ float xs[16][FIN_];          // 16 KB
  for (int t = threadIdx.x; t < 16 * FIN_; t += 128) {
    int r = t >> 8, k = t & 255;
    xs[r][k] = ldin(x, (long)(row0 + r) * FIN_ + k, isbf);
  }
  __syncthreads();

  float acc[16];
#pragma unroll
  for (int r = 0; r < 16; r++) acc[r] = 0.f;

#pragma unroll 4
  for (int k = 0; k < FIN_; k++) {
    float w = ldin(W, (long)k * FOUT_ + j, isbf);
#pragma unroll
    for (int r = 0; r < 16; r++) acc[r] += xs[r][k] * w;
  }

#pragma unroll
  for (int r = 0; r < 16; r++) h[(long)(row0 + r) * FOUT_ + j] = acc[r];

  // f_src / f_dst: dot each h-row with a[:128] and a[128:]
  float aj  = ldin(a, j, isbf);
  float ajd = ldin(a, FOUT_ + j, isbf);
  float ps[16], pd[16];
#pragma unroll
  for (int r = 0; r < 16; r++) { ps[r] = acc[r] * aj; pd[r] = acc[r] * ajd; }
#pragma unroll
  for (int off = 32; off >= 1; off >>= 1) {
#pragma unroll
    for (int r = 0; r < 16; r++) {
      ps[r] += __shfl_xor(ps[r], off, 64);
      pd[r] += __shfl_xor(pd[r], off, 64);
    }
  }
  __shared__ float red[2][16][2];
  int wv = threadIdx.x >> 6;
  if ((threadIdx.x & 63) == 0) {
#pragma unroll
    for (int r = 0; r < 16; r++) { red[wv][r][0] = ps[r]; red[wv][r][1] = pd[r]; }
  }
  __syncthreads();
  if (threadIdx.x < 32) {
    int r = threadIdx.x >> 1, s = threadIdx.x & 1;
    float v = red[0][r][s] + red[1][r][s];
    if (s) fdst[row0 + r] = v; else fsrc[row0 + r] = v;
  }
}

// ---------- kernel 2: per-batch max of f_dst (for softmax upper bound) ----------
__global__ void k_mdst(const float* __restrict__ fdst, float* __restrict__ Mdst) {
  int b = blockIdx.x;
  float m = -1e30f;
  for (int i = threadIdx.x; i < N_; i += 256) m = fmaxf(m, fdst[b * N_ + i]);
  __shared__ float red[256];
  red[threadIdx.x] = m;
  __syncthreads();
  for (int s = 128; s > 0; s >>= 1) {
    if (threadIdx.x < s) red[threadIdx.x] = fmaxf(red[threadIdx.x], red[threadIdx.x + s]);
    __syncthreads();
  }
  if (threadIdx.x == 0) Mdst[b] = red[0];
}

// ---------- kernel 3: fused gated attention + softmax + PV + elu ----------
// grid = B * (N/32) blocks of 256 threads. TQ=32 queries/block, TJ=64 key tile.
// Softmax uses static bound Bq = max(0, fsrc[q] + max_j fdst[j]) >= max logit,
// valid because loc <= 1 and gated entries contribute exactly 0. Diagonal
// (loc=1) guarantees a nonzero denominator.
__global__ __launch_bounds__(256)
void k_attn(const float* __restrict__ h, const void* __restrict__ coord,
            const float* __restrict__ fsrc, const float* __restrict__ fdst,
            const float* __restrict__ Mdst, const int* __restrict__ flag,
            void* __restrict__ out) {
  const int isbf = *flag;
  const int tid  = threadIdx.x;
  const int b    = blockIdx.x >> 6;
  const int q0g  = (blockIdx.x & 63) * 32;

  __shared__ __align__(16) float pbuf[64][32];   // p[jl][q]   8 KB
  __shared__ __align__(16) float hs[64][FOUT_];  // h tile    32 KB
  __shared__ float cjs[64][4];
  __shared__ float fdj[64];
  __shared__ float lred[8][32];
  __shared__ float lfin[32];

  // logits role: one query per thread, 8 j's per tile
  const int qA    = tid & 31;
  const int jseg  = tid >> 5;               // 0..7
  const long qglb = (long)b * N_ + q0g + qA;
  const float cq0 = ldin(coord, qglb * 3 + 0, isbf);
  const float cq1 = ldin(coord, qglb * 3 + 1, isbf);
  const float cq2 = ldin(coord, qglb * 3 + 2, isbf);
  const float fsq = fsrc[qglb];
  const float Bq  = fmaxf(0.f, fsq + Mdst[b]);
  float lacc = 0.f;

  // PV role: 4 queries x 4 features per thread
  const int f0 = (tid & 31) * 4;
  const int qg = tid >> 5;                  // 0..7 -> queries qg*4..qg*4+3
  float4 acc0 = {0,0,0,0}, acc1 = {0,0,0,0}, acc2 = {0,0,0,0}, acc3 = {0,0,0,0};

  const int hrow = tid >> 2;                // 0..63
  const int hcol = (tid & 3) * 32;

  for (int j0 = 0; j0 < N_; j0 += 64) {
    // ---- stage h tile + coords + fdst ----
    const float4* hg = (const float4*)(h + ((size_t)(b * N_ + j0 + hrow)) * FOUT_ + hcol);
    float4* hl = (float4*)&hs[hrow][hcol];
#pragma unroll
    for (int t = 0; t < 8; t++) hl[t] = hg[t];
    if (tid < 64) {
      long jg = (long)b * N_ + j0 + tid;
      cjs[tid][0] = ldin(coord, jg * 3 + 0, isbf);
      cjs[tid][1] = ldin(coord, jg * 3 + 1, isbf);
      cjs[tid][2] = ldin(coord, jg * 3 + 2, isbf);
      fdj[tid]    = fdst[jg];
    }
    __syncthreads();

    // ---- logits -> p ----
#pragma unroll
    for (int jj = 0; jj < 8; jj++) {
      int jl = jseg * 8 + jj;
      float dx = cq0 - cjs[jl][0];
      float dy = cq1 - cjs[jl][1];
      float dz = cq2 - cjs[jl][2];
      float d2 = dx * dx + dy * dy + dz * dz;
      float loc = __expf(-0.1f * d2);
      float e = fsq + fdj[jl];
      e = (e > 0.f) ? e : 0.2f * e;          // leaky relu
      float p = 0.f;
      if (loc > 0.01f) p = __expf(e * loc - Bq);
      lacc += p;
      pbuf[jl][qA] = p;
    }
    __syncthreads();

    // ---- PV: acc[qi][fi] += p[jl][qg*4+qi] * hs[jl][f0+fi] ----
#pragma unroll 8
    for (int jl = 0; jl < 64; jl++) {
      float4 pv = *(const float4*)&pbuf[jl][qg * 4];
      float4 hv = *(const float4*)&hs[jl][f0];
      acc0.x += pv.x * hv.x; acc0.y += pv.x * hv.y; acc0.z += pv.x * hv.z; acc0.w += pv.x * hv.w;
      acc1.x += pv.y * hv.x; acc1.y += pv.y * hv.y; acc1.z += pv.y * hv.z; acc1.w += pv.y * hv.w;
      acc2.x += pv.z * hv.x; acc2.y += pv.z * hv.y; acc2.z += pv.z * hv.z; acc2.w += pv.z * hv.w;
      acc3.x += pv.w * hv.x; acc3.y += pv.w * hv.y; acc3.z += pv.w * hv.z; acc3.w += pv.w * hv.w;
    }
    __syncthreads();
  }

  // ---- denominator reduction ----
  lred[jseg][qA] = lacc;
  __syncthreads();
  if (tid < 32) {
    float s = 0.f;
#pragma unroll
    for (int k = 0; k < 8; k++) s += lred[k][tid];
    lfin[tid] = 1.0f / s;
  }
  __syncthreads();

  // ---- normalize, elu, store ----
  float4 accs[4] = {acc0, acc1, acc2, acc3};
#pragma unroll
  for (int qi = 0; qi < 4; qi++) {
    float inv = lfin[qg * 4 + qi];
    float4 v = accs[qi];
    v.x *= inv; v.y *= inv; v.z *= inv; v.w *= inv;
    v.x = (v.x > 0.f) ? v.x : expm1f(v.x);
    v.y = (v.y > 0.f) ? v.y : expm1f(v.y);
    v.z = (v.z > 0.f) ? v.z : expm1f(v.z);
    v.w = (v.w > 0.f) ? v.w : expm1f(v.w);
    size_t oidx = ((size_t)(b * N_ + q0g + qg * 4 + qi)) * FOUT_ + f0;
    if (isbf) {
      unsigned short b0 = f2bf(v.x), b1 = f2bf(v.y), b2 = f2bf(v.z), b3 = f2bf(v.w);
      uint2 u = make_uint2((unsigned)b0 | ((unsigned)b1 << 16),
                           (unsigned)b2 | ((unsigned)b3 << 16));
      *(uint2*)((unsigned short*)out + oidx) = u;
    } else {
      *(float4*)((float*)out + oidx) = v;
    }
  }
}

extern "C" void kernel_launch(void* const* d_in, const int* in_sizes, int n_in,
                              void* d_out, int out_size, void* d_ws, size_t ws_size,
                              hipStream_t stream) {
  const void* x     = d_in[0];
  const void* coord = d_in[1];
  const void* W     = d_in[2];
  const void* a     = d_in[3];

  // workspace layout (floats): [0..63] header/flag, then h, fsrc, fdst, Mdst
  int*   flag = (int*)d_ws;
  float* wsf  = (float*)d_ws;
  float* h    = wsf + 64;
  float* fsrc = h + (size_t)B_ * N_ * FOUT_;
  float* fdst = fsrc + (size_t)B_ * N_;
  float* Mdst = fdst + (size_t)B_ * N_;

  k_detect<<<1, 256, 0, stream>>>(x, flag);
  k_h<<<B_ * N_ / 16, 128, 0, stream>>>(x, W, a, flag, h, fsrc, fdst);
  k_mdst<<<B_, 256, 0, stream>>>(fdst, Mdst);
  k_attn<<<B_ * (N_ / 32), 256, 0, stream>>>(h, coord, fsrc, fdst, Mdst, flag, d_out);
}

// Round 5
// 188.291 us; speedup vs baseline: 1.7954x; 1.7954x over previous
//
#include <hip/hip_runtime.h>
#include <hip/hip_bf16.h>

#define B_    8
#define N_    2048
#define FIN_  256
#define FOUT_ 128
#define NROWS (B_*N_)

typedef __attribute__((ext_vector_type(8))) short short8;
typedef __attribute__((ext_vector_type(4))) float f32x4;

__device__ __forceinline__ float bf2f(unsigned short u) {
  return __uint_as_float(((unsigned int)u) << 16);
}
__device__ __forceinline__ unsigned short f2bf(float f) {
  unsigned int u = __float_as_uint(f);
  u += 0x7FFFu + ((u >> 16) & 1u);   // RNE; exact identity for bf16-origin floats
  return (unsigned short)(u >> 16);
}
// dtype-agnostic input load (isbf: 1 = bf16 tensor, 0 = fp32 tensor)
__device__ __forceinline__ float ldin(const void* p, size_t idx, int isbf) {
  if (isbf) return bf2f(((const unsigned short*)p)[idx]);
  return ((const float*)p)[idx];
}

// ---------- kernel A: detect input dtype from x's bit patterns ----------
// bf16 N(0,1): ~100% of u16s have exponent in [110,145] (or +-0).
// fp32 viewed as u16: odd halves plausible, even halves random mantissa
// bits (~14% plausible) -> ~57% total. Threshold 90%. Deterministic.
__global__ void k_detect(const void* x, int* flag) {
  __shared__ int cnt[256];
  const unsigned short* u = (const unsigned short*)x;
  int c = 0;
  for (int i = threadIdx.x; i < 16384; i += 256) {
    unsigned short v = u[i];
    int e = (v >> 7) & 0xFF;
    if ((e >= 110 && e <= 145) || (v & 0x7FFF) == 0) c++;
  }
  cnt[threadIdx.x] = c;
  __syncthreads();
  for (int s = 128; s > 0; s >>= 1) {
    if (threadIdx.x < s) cnt[threadIdx.x] += cnt[threadIdx.x + s];
    __syncthreads();
  }
  if (threadIdx.x == 0) *flag = (cnt[0] > 14745) ? 1 : 0;  // 0.9 * 16384
}

// ---------- kernel 0: W [256][128] -> WT hi/lo [128][256] (bf16 split) ------
__global__ __launch_bounds__(256)
void k_wt(const void* __restrict__ W, const int* __restrict__ flag,
          unsigned short* __restrict__ WThi, unsigned short* __restrict__ WTlo) {
  const int isbf = *flag;
  int f = blockIdx.x;        // 0..127
  int k = threadIdx.x;       // 0..255
  float w = ldin(W, (size_t)k * 128 + f, isbf);
  unsigned short hi = f2bf(w);
  WThi[f * 256 + k] = hi;
  WTlo[f * 256 + k] = f2bf(w - bf2f(hi));
}

// ---------- kernel 1: h = x@W via hi/lo-split MFMA; emit hT + fsrc/fdst ----
// hT layout: (row j, feat f) at hT[(j>>4)*2048 + f*16 + (j&15)]: a B-fragment
// (8 consecutive j, fixed f) is one contiguous 16B read.
// Block: 64 rows x 128 cols, 4 waves; wave w owns rows [w*16, w*16+16).
// Precision: acc = xh*wh + xl*wh + xh*wl ~ fp32-quality, so fsrc/fdst (the
// error-amplified logit path) stay accurate; hT stores bf16(acc) for PV.
__global__ __launch_bounds__(256)
void k_h(const void* __restrict__ x, const unsigned short* __restrict__ WThi,
         const unsigned short* __restrict__ WTlo,
         const void* __restrict__ a, const int* __restrict__ flag,
         unsigned short* __restrict__ hT, float* __restrict__ fsrc, float* __restrict__ fdst) {
  __shared__ __align__(16) unsigned short xh_s[64][264];  // pad: 16B-aligned rows
  __shared__ __align__(16) unsigned short xl_s[64][264];
  __shared__ float as_s[FOUT_], ad_s[FOUT_];

  const int isbf = *flag;
  const int t    = threadIdx.x;
  const int row0 = blockIdx.x * 64;

  if (t < FOUT_) {
    as_s[t] = ldin(a, t, isbf);
    ad_s[t] = ldin(a, FOUT_ + t, isbf);
  }

  if (isbf) {
    const unsigned short* xu = (const unsigned short*)x;
#pragma unroll
    for (int u = 0; u < 8; u++) {
      int r = u * 8 + (t >> 5), c = t & 31;
      *(short8*)&xh_s[r][c * 8] = *(const short8*)&xu[(size_t)(row0 + r) * FIN_ + c * 8];
      short8 z = {0, 0, 0, 0, 0, 0, 0, 0};
      *(short8*)&xl_s[r][c * 8] = z;
    }
  } else {
    const float* xf = (const float*)x;
#pragma unroll
    for (int u = 0; u < 8; u++) {
      int r = u * 8 + (t >> 5), c = t & 31;
      float4 v0 = *(const float4*)&xf[(size_t)(row0 + r) * FIN_ + c * 8];
      float4 v1 = *(const float4*)&xf[(size_t)(row0 + r) * FIN_ + c * 8 + 4];
      float vv[8] = {v0.x, v0.y, v0.z, v0.w, v1.x, v1.y, v1.z, v1.w};
      short8 sh, sl;
#pragma unroll
      for (int e = 0; e < 8; e++) {
        unsigned short hb = f2bf(vv[e]);
        sh[e] = (short)hb;
        sl[e] = (short)f2bf(vv[e] - bf2f(hb));
      }
      *(short8*)&xh_s[r][c * 8] = sh;
      *(short8*)&xl_s[r][c * 8] = sl;
    }
  }
  __syncthreads();

  const int lane = t & 63, w = t >> 6;
  const int m = lane & 15, quad = lane >> 4;

  f32x4 acc[8];
#pragma unroll
  for (int i = 0; i < 8; i++) acc[i] = (f32x4){0.f, 0.f, 0.f, 0.f};

#pragma unroll
  for (int ks = 0; ks < 8; ks++) {
    short8 ah = *(const short8*)&xh_s[w * 16 + m][ks * 32 + quad * 8];
    short8 al = *(const short8*)&xl_s[w * 16 + m][ks * 32 + quad * 8];
#pragma unroll
    for (int ft = 0; ft < 8; ft++) {
      short8 bh = *(const short8*)&WThi[(size_t)(ft * 16 + m) * 256 + ks * 32 + quad * 8];
      short8 bl = *(const short8*)&WTlo[(size_t)(ft * 16 + m) * 256 + ks * 32 + quad * 8];
      acc[ft] = __builtin_amdgcn_mfma_f32_16x16x32_bf16(ah, bh, acc[ft], 0, 0, 0);
      acc[ft] = __builtin_amdgcn_mfma_f32_16x16x32_bf16(al, bh, acc[ft], 0, 0, 0);
      acc[ft] = __builtin_amdgcn_mfma_f32_16x16x32_bf16(ah, bl, acc[ft], 0, 0, 0);
    }
  }

  // D layout: row = quad*4 + r (within wave's 16-row slab), col = ft*16 + m
  size_t n0 = (size_t)blockIdx.x * 4 + w;            // global 16-row chunk index
  unsigned short* hblk = hT + n0 * (FOUT_ * 16);
  float ps[4] = {0, 0, 0, 0}, pd[4] = {0, 0, 0, 0};
#pragma unroll
  for (int ft = 0; ft < 8; ft++) {
    int col = ft * 16 + m;
    float av = as_s[col], dv = ad_s[col];
    float v0 = acc[ft][0], v1 = acc[ft][1], v2 = acc[ft][2], v3 = acc[ft][3];
    unsigned short pk0 = f2bf(v0), pk1 = f2bf(v1), pk2 = f2bf(v2), pk3 = f2bf(v3);
    ps[0] += v0 * av; pd[0] += v0 * dv;
    ps[1] += v1 * av; pd[1] += v1 * dv;
    ps[2] += v2 * av; pd[2] += v2 * dv;
    ps[3] += v3 * av; pd[3] += v3 * dv;
    *(uint2*)&hblk[col * 16 + quad * 4] = make_uint2(
        (unsigned)pk0 | ((unsigned)pk1 << 16),
        (unsigned)pk2 | ((unsigned)pk3 << 16));
  }
#pragma unroll
  for (int off = 8; off >= 1; off >>= 1) {
#pragma unroll
    for (int r = 0; r < 4; r++) {
      ps[r] += __shfl_xor(ps[r], off, 64);
      pd[r] += __shfl_xor(pd[r], off, 64);
    }
  }
  if (m == 0) {
#pragma unroll
    for (int r = 0; r < 4; r++) {
      int grow = row0 + w * 16 + quad * 4 + r;
      fsrc[grow] = ps[r];
      fdst[grow] = pd[r];
    }
  }
}

// ---------- kernel 2: per-batch max of f_dst ----------
__global__ void k_mdst(const float* __restrict__ fdst, float* __restrict__ Mdst) {
  int b = blockIdx.x;
  float mx = -1e30f;
  for (int i = threadIdx.x; i < N_; i += 256) mx = fmaxf(mx, fdst[b * N_ + i]);
  __shared__ float red[256];
  red[threadIdx.x] = mx;
  __syncthreads();
  for (int s = 128; s > 0; s >>= 1) {
    if (threadIdx.x < s) red[threadIdx.x] = fmaxf(red[threadIdx.x], red[threadIdx.x + s]);
    __syncthreads();
  }
  if (threadIdx.x == 0) Mdst[b] = red[0];
}

// ---------- kernel 3: gated attention, PV via bf16 MFMA (p split hi/lo) -----
// Block = 32 queries, 4 waves; wave w owns features [w*32, w*32+32).
// Static softmax bound Bq = max(0, fsrc[q] + max_j fdst[j]) (loc<=1; diagonal
// guarantees nonzero denominator). Output store dtype-branched like inputs.
__global__ __launch_bounds__(256)
void k_attn(const unsigned short* __restrict__ hT, const void* __restrict__ coord,
            const float* __restrict__ fsrc, const float* __restrict__ fdst,
            const float* __restrict__ Mdst, const int* __restrict__ flag,
            void* __restrict__ out) {
  const int isbf = *flag;
  const int tid = threadIdx.x;
  const int b   = blockIdx.x >> 6;
  const int q0  = (blockIdx.x & 63) * 32;

  __shared__ __align__(16) unsigned short phi[32][72];  // pad 72: 16B-aligned rows
  __shared__ __align__(16) unsigned short plo[32][72];
  __shared__ float cjs[64][4];
  __shared__ float fdj[64];
  __shared__ float lred[8][32];
  __shared__ float lfin[32];

  // logits role
  const int qA   = tid & 31;
  const int jseg = tid >> 5;                 // 0..7, 8 j's each per 64-tile
  const size_t qglb = (size_t)b * N_ + q0 + qA;
  const float cq0 = ldin(coord, qglb * 3 + 0, isbf);
  const float cq1 = ldin(coord, qglb * 3 + 1, isbf);
  const float cq2 = ldin(coord, qglb * 3 + 2, isbf);
  const float fsq = fsrc[qglb];
  const float Bq  = fmaxf(0.f, fsq + Mdst[b]);
  float lacc = 0.f;

  // MFMA role
  const int lane = tid & 63, w = tid >> 6;
  const int m = lane & 15, quad = lane >> 4;
  f32x4 acc[2][2];                           // [qt][f2], f-tile = w*2 + f2
#pragma unroll
  for (int i = 0; i < 2; i++)
#pragma unroll
    for (int j = 0; j < 2; j++) acc[i][j] = (f32x4){0.f, 0.f, 0.f, 0.f};

  const unsigned short* hTb = hT + (size_t)b * (N_ * FOUT_);

  for (int j0 = 0; j0 < N_; j0 += 64) {
    if (tid < 64) {
      size_t jg = (size_t)b * N_ + j0 + tid;
      cjs[tid][0] = ldin(coord, jg * 3 + 0, isbf);
      cjs[tid][1] = ldin(coord, jg * 3 + 1, isbf);
      cjs[tid][2] = ldin(coord, jg * 3 + 2, isbf);
      fdj[tid]    = fdst[jg];
    }
    __syncthreads();

    // ---- logits -> p (fp32), split to bf16 hi/lo, scalar LDS stores ----
#pragma unroll
    for (int jj = 0; jj < 8; jj++) {
      int jl = jseg * 8 + jj;
      float dx = cq0 - cjs[jl][0];
      float dy = cq1 - cjs[jl][1];
      float dz = cq2 - cjs[jl][2];
      float d2 = dx * dx + dy * dy + dz * dz;
      float loc = __expf(-0.1f * d2);
      float e = fsq + fdj[jl];
      e = (e > 0.f) ? e : 0.2f * e;
      float p = (loc > 0.01f) ? __expf(e * loc - Bq) : 0.f;
      lacc += p;
      unsigned short hb = f2bf(p);
      phi[qA][jl] = hb;
      plo[qA][jl] = f2bf(p - bf2f(hb));
    }
    __syncthreads();

    // ---- PV MFMA: 2 k-steps of 32 ----
    const int jc = j0 >> 4;
#pragma unroll
    for (int ks = 0; ks < 2; ks++) {
      short8 bfr[2];
#pragma unroll
      for (int f2 = 0; f2 < 2; f2++) {
        int col = (w * 2 + f2) * 16 + m;
        bfr[f2] = *(const short8*)&hTb[(size_t)(jc + ks * 2 + (quad >> 1)) * (FOUT_ * 16)
                                       + col * 16 + (quad & 1) * 8];
      }
      short8 ah0 = *(const short8*)&phi[m][ks * 32 + quad * 8];
      short8 al0 = *(const short8*)&plo[m][ks * 32 + quad * 8];
      short8 ah1 = *(const short8*)&phi[16 + m][ks * 32 + quad * 8];
      short8 al1 = *(const short8*)&plo[16 + m][ks * 32 + quad * 8];
#pragma unroll
      for (int f2 = 0; f2 < 2; f2++) {
        acc[0][f2] = __builtin_amdgcn_mfma_f32_16x16x32_bf16(ah0, bfr[f2], acc[0][f2], 0, 0, 0);
        acc[0][f2] = __builtin_amdgcn_mfma_f32_16x16x32_bf16(al0, bfr[f2], acc[0][f2], 0, 0, 0);
        acc[1][f2] = __builtin_amdgcn_mfma_f32_16x16x32_bf16(ah1, bfr[f2], acc[1][f2], 0, 0, 0);
        acc[1][f2] = __builtin_amdgcn_mfma_f32_16x16x32_bf16(al1, bfr[f2], acc[1][f2], 0, 0, 0);
      }
    }
    __syncthreads();
  }

  // ---- denominator ----
  lred[jseg][qA] = lacc;
  __syncthreads();
  if (tid < 32) {
    float s = 0.f;
#pragma unroll
    for (int k = 0; k < 8; k++) s += lred[k][tid];
    lfin[tid] = 1.0f / fmaxf(s, 1e-30f);
  }
  __syncthreads();

  // ---- normalize, elu, store (D: row = qt*16+quad*4+r, col = ftile*16+m) ----
#pragma unroll
  for (int qt = 0; qt < 2; qt++) {
#pragma unroll
    for (int f2 = 0; f2 < 2; f2++) {
      int col = (w * 2 + f2) * 16 + m;
#pragma unroll
      for (int r = 0; r < 4; r++) {
        int row = qt * 16 + quad * 4 + r;
        float v = acc[qt][f2][r] * lfin[row];
        v = (v > 0.f) ? v : expm1f(v);
        size_t oidx = ((size_t)(b * N_ + q0 + row)) * FOUT_ + col;
        if (isbf) ((unsigned short*)out)[oidx] = f2bf(v);
        else      ((float*)out)[oidx] = v;
      }
    }
  }
}

extern "C" void kernel_launch(void* const* d_in, const int* in_sizes, int n_in,
                              void* d_out, int out_size, void* d_ws, size_t ws_size,
                              hipStream_t stream) {
  const void* x     = d_in[0];
  const void* coord = d_in[1];
  const void* W     = d_in[2];
  const void* a     = d_in[3];

  // ws layout: [64 floats flag/header][hT bf16][WThi][WTlo][fsrc][fdst][Mdst]
  int*            flag = (int*)d_ws;
  unsigned short* hT   = (unsigned short*)((float*)d_ws + 64);
  unsigned short* WThi = hT + (size_t)NROWS * FOUT_;
  unsigned short* WTlo = WThi + 128 * 256;
  float*          fsrc = (float*)(WTlo + 128 * 256);
  float*          fdst = fsrc + NROWS;
  float*          Mdst = fdst + NROWS;

  k_detect<<<1, 256, 0, stream>>>(x, flag);
  k_wt    <<<128, 256, 0, stream>>>(W, flag, WThi, WTlo);
  k_h     <<<NROWS / 64, 256, 0, stream>>>(x, WThi, WTlo, a, flag, hT, fsrc, fdst);
  k_mdst  <<<B_, 256, 0, stream>>>(fdst, Mdst);
  k_attn  <<<B_ * (N_ / 32), 256, 0, stream>>>(hT, coord, fsrc, fdst, Mdst, flag, d_out);
}

// Round 7
// 172.122 us; speedup vs baseline: 1.9640x; 1.0939x over previous
//
#include <hip/hip_runtime.h>
#include <hip/hip_bf16.h>

#define B_    8
#define N_    2048
#define FIN_  256
#define FOUT_ 128
#define NROWS (B_*N_)

typedef __attribute__((ext_vector_type(8))) short short8;
typedef __attribute__((ext_vector_type(4))) float f32x4;

__device__ __forceinline__ float bf2f(unsigned short u) {
  return __uint_as_float(((unsigned int)u) << 16);
}
__device__ __forceinline__ unsigned short f2bf(float f) {
  unsigned int u = __float_as_uint(f);
  u += 0x7FFFu + ((u >> 16) & 1u);   // RNE; exact identity for bf16-origin floats
  return (unsigned short)(u >> 16);
}
// dtype-agnostic input load (isbf: 1 = bf16 tensor, 0 = fp32 tensor)
__device__ __forceinline__ float ldin(const void* p, size_t idx, int isbf) {
  if (isbf) return bf2f(((const unsigned short*)p)[idx]);
  return ((const float*)p)[idx];
}

// ---------- kernel A: detect input dtype from x's bit patterns ----------
__global__ void k_detect(const void* x, int* flag) {
  __shared__ int cnt[256];
  const unsigned short* u = (const unsigned short*)x;
  int c = 0;
  for (int i = threadIdx.x; i < 16384; i += 256) {
    unsigned short v = u[i];
    int e = (v >> 7) & 0xFF;
    if ((e >= 110 && e <= 145) || (v & 0x7FFF) == 0) c++;
  }
  cnt[threadIdx.x] = c;
  __syncthreads();
  for (int s = 128; s > 0; s >>= 1) {
    if (threadIdx.x < s) cnt[threadIdx.x] += cnt[threadIdx.x + s];
    __syncthreads();
  }
  if (threadIdx.x == 0) *flag = (cnt[0] > 14745) ? 1 : 0;  // 0.9 * 16384
}

// ---------- kernel 0: W [256][128] -> WT hi/lo [128][256] (bf16 split) ------
__global__ __launch_bounds__(256)
void k_wt(const void* __restrict__ W, const int* __restrict__ flag,
          unsigned short* __restrict__ WThi, unsigned short* __restrict__ WTlo) {
  const int isbf = *flag;
  int f = blockIdx.x;        // 0..127
  int k = threadIdx.x;       // 0..255
  float w = ldin(W, (size_t)k * 128 + f, isbf);
  unsigned short hi = f2bf(w);
  WThi[f * 256 + k] = hi;
  WTlo[f * 256 + k] = f2bf(w - bf2f(hi));
}

// ---------- kernel 1: h = x@W via hi/lo-split MFMA; emit hT + fsrc/fdst ----
// hT layout: (row j, feat f) at hT[(j>>4)*2048 + f*16 + (j&15)].
__global__ __launch_bounds__(256)
void k_h(const void* __restrict__ x, const unsigned short* __restrict__ WThi,
         const unsigned short* __restrict__ WTlo,
         const void* __restrict__ a, const int* __restrict__ flag,
         unsigned short* __restrict__ hT, float* __restrict__ fsrc, float* __restrict__ fdst) {
  __shared__ __align__(16) unsigned short xh_s[64][264];
  __shared__ __align__(16) unsigned short xl_s[64][264];
  __shared__ float as_s[FOUT_], ad_s[FOUT_];

  const int isbf = *flag;
  const int t    = threadIdx.x;
  const int row0 = blockIdx.x * 64;

  if (t < FOUT_) {
    as_s[t] = ldin(a, t, isbf);
    ad_s[t] = ldin(a, FOUT_ + t, isbf);
  }

  if (isbf) {
    const unsigned short* xu = (const unsigned short*)x;
#pragma unroll
    for (int u = 0; u < 8; u++) {
      int r = u * 8 + (t >> 5), c = t & 31;
      *(short8*)&xh_s[r][c * 8] = *(const short8*)&xu[(size_t)(row0 + r) * FIN_ + c * 8];
      short8 z = {0, 0, 0, 0, 0, 0, 0, 0};
      *(short8*)&xl_s[r][c * 8] = z;
    }
  } else {
    const float* xf = (const float*)x;
#pragma unroll
    for (int u = 0; u < 8; u++) {
      int r = u * 8 + (t >> 5), c = t & 31;
      float4 v0 = *(const float4*)&xf[(size_t)(row0 + r) * FIN_ + c * 8];
      float4 v1 = *(const float4*)&xf[(size_t)(row0 + r) * FIN_ + c * 8 + 4];
      float vv[8] = {v0.x, v0.y, v0.z, v0.w, v1.x, v1.y, v1.z, v1.w};
      short8 sh, sl;
#pragma unroll
      for (int e = 0; e < 8; e++) {
        unsigned short hb = f2bf(vv[e]);
        sh[e] = (short)hb;
        sl[e] = (short)f2bf(vv[e] - bf2f(hb));
      }
      *(short8*)&xh_s[r][c * 8] = sh;
      *(short8*)&xl_s[r][c * 8] = sl;
    }
  }
  __syncthreads();

  const int lane = t & 63, w = t >> 6;
  const int m = lane & 15, quad = lane >> 4;

  f32x4 acc[8];
#pragma unroll
  for (int i = 0; i < 8; i++) acc[i] = (f32x4){0.f, 0.f, 0.f, 0.f};

#pragma unroll
  for (int ks = 0; ks < 8; ks++) {
    short8 ah = *(const short8*)&xh_s[w * 16 + m][ks * 32 + quad * 8];
    short8 al = *(const short8*)&xl_s[w * 16 + m][ks * 32 + quad * 8];
#pragma unroll
    for (int ft = 0; ft < 8; ft++) {
      short8 bh = *(const short8*)&WThi[(size_t)(ft * 16 + m) * 256 + ks * 32 + quad * 8];
      short8 bl = *(const short8*)&WTlo[(size_t)(ft * 16 + m) * 256 + ks * 32 + quad * 8];
      acc[ft] = __builtin_amdgcn_mfma_f32_16x16x32_bf16(ah, bh, acc[ft], 0, 0, 0);
      acc[ft] = __builtin_amdgcn_mfma_f32_16x16x32_bf16(al, bh, acc[ft], 0, 0, 0);
      acc[ft] = __builtin_amdgcn_mfma_f32_16x16x32_bf16(ah, bl, acc[ft], 0, 0, 0);
    }
  }

  size_t n0 = (size_t)blockIdx.x * 4 + w;
  unsigned short* hblk = hT + n0 * (FOUT_ * 16);
  float ps[4] = {0, 0, 0, 0}, pd[4] = {0, 0, 0, 0};
#pragma unroll
  for (int ft = 0; ft < 8; ft++) {
    int col = ft * 16 + m;
    float av = as_s[col], dv = ad_s[col];
    float v0 = acc[ft][0], v1 = acc[ft][1], v2 = acc[ft][2], v3 = acc[ft][3];
    unsigned short pk0 = f2bf(v0), pk1 = f2bf(v1), pk2 = f2bf(v2), pk3 = f2bf(v3);
    ps[0] += v0 * av; pd[0] += v0 * dv;
    ps[1] += v1 * av; pd[1] += v1 * dv;
    ps[2] += v2 * av; pd[2] += v2 * dv;
    ps[3] += v3 * av; pd[3] += v3 * dv;
    *(uint2*)&hblk[col * 16 + quad * 4] = make_uint2(
        (unsigned)pk0 | ((unsigned)pk1 << 16),
        (unsigned)pk2 | ((unsigned)pk3 << 16));
  }
#pragma unroll
  for (int off = 8; off >= 1; off >>= 1) {
#pragma unroll
    for (int r = 0; r < 4; r++) {
      ps[r] += __shfl_xor(ps[r], off, 64);
      pd[r] += __shfl_xor(pd[r], off, 64);
    }
  }
  if (m == 0) {
#pragma unroll
    for (int r = 0; r < 4; r++) {
      int grow = row0 + w * 16 + quad * 4 + r;
      fsrc[grow] = ps[r];
      fdst[grow] = pd[r];
    }
  }
}

// ---------- kernel 2: per-batch max of f_dst ----------
__global__ void k_mdst(const float* __restrict__ fdst, float* __restrict__ Mdst) {
  int b = blockIdx.x;
  float mx = -1e30f;
  for (int i = threadIdx.x; i < N_; i += 256) mx = fmaxf(mx, fdst[b * N_ + i]);
  __shared__ float red[256];
  red[threadIdx.x] = mx;
  __syncthreads();
  for (int s = 128; s > 0; s >>= 1) {
    if (threadIdx.x < s) red[threadIdx.x] = fmaxf(red[threadIdx.x], red[threadIdx.x + s]);
    __syncthreads();
  }
  if (threadIdx.x == 0) Mdst[b] = red[0];
}

// ---------- kernel 3: gated attention, round-5 dataflow, 16-q blocks --------
// Grid = B*(N/16) = 1024 blocks (4/CU), 256 threads. Same verified pieces as
// round 5 (p -> LDS phi/plo -> ds_read A-frag -> MFMA; B-frag from hT), but:
//  * double-buffered phi/plo/cjs => exactly ONE barrier per 64-j tile.
//    Safety: iter k's MFMA reads phi[buf] finish before sync_{k+1} (barrier
//    drains lgkm); phi[buf] is rewritten only after sync_{k+1}.
//  * wave w owns features [w*32, w*32+32) for all 2048 j; no cross-wave
//    combine needed.
__global__ __launch_bounds__(256)
void k_attn(const unsigned short* __restrict__ hT, const void* __restrict__ coord,
            const float* __restrict__ fsrc, const float* __restrict__ fdst,
            const float* __restrict__ Mdst, const int* __restrict__ flag,
            void* __restrict__ out) {
  const int isbf = *flag;
  const int tid = threadIdx.x;
  const int b   = blockIdx.x >> 7;          // 128 q-blocks per batch
  const int q0  = (blockIdx.x & 127) * 16;

  __shared__ __align__(16) unsigned short phi[2][16][72];
  __shared__ __align__(16) unsigned short plo[2][16][72];
  __shared__ __align__(16) float cjs[2][64][4];   // (cx,cy,cz,fdst)
  __shared__ float lred[16][16];                  // [jseg][qA]

  // logit role: query qA, j-segment jseg (4 j's per 64-tile)
  const int qA   = tid & 15;
  const int jseg = tid >> 4;                 // 0..15
  const size_t qglb = (size_t)b * N_ + q0 + qA;
  const float cq0 = ldin(coord, qglb * 3 + 0, isbf);
  const float cq1 = ldin(coord, qglb * 3 + 1, isbf);
  const float cq2 = ldin(coord, qglb * 3 + 2, isbf);
  const float fsq = fsrc[qglb];
  const float Bq  = fmaxf(0.f, fsq + Mdst[b]);
  float lacc = 0.f;

  // MFMA role
  const int lane = tid & 63, w = tid >> 6;
  const int m = lane & 15, quad = lane >> 4;
  f32x4 acc[2];                              // f-tile = w*2 + f2
  acc[0] = (f32x4){0.f, 0.f, 0.f, 0.f};
  acc[1] = (f32x4){0.f, 0.f, 0.f, 0.f};

  const unsigned short* hTb = hT + (size_t)b * (N_ * FOUT_);

  // preload tile 0 coords
  if (tid < 64) {
    size_t jg = (size_t)b * N_ + tid;
    cjs[0][tid][0] = ldin(coord, jg * 3 + 0, isbf);
    cjs[0][tid][1] = ldin(coord, jg * 3 + 1, isbf);
    cjs[0][tid][2] = ldin(coord, jg * 3 + 2, isbf);
    cjs[0][tid][3] = fdst[jg];
  }
  __syncthreads();

  for (int t64 = 0; t64 < 32; t64++) {
    const int buf = t64 & 1, nbuf = buf ^ 1;
    const int j0 = t64 * 64;

    // stage NEXT tile's coords into the other buffer
    if (t64 < 31 && tid < 64) {
      size_t jg = (size_t)b * N_ + j0 + 64 + tid;
      cjs[nbuf][tid][0] = ldin(coord, jg * 3 + 0, isbf);
      cjs[nbuf][tid][1] = ldin(coord, jg * 3 + 1, isbf);
      cjs[nbuf][tid][2] = ldin(coord, jg * 3 + 2, isbf);
      cjs[nbuf][tid][3] = fdst[jg];
    }

    // ---- logits -> p (fp32), split to bf16 hi/lo, scalar LDS stores ----
#pragma unroll
    for (int jj = 0; jj < 4; jj++) {
      int jl = jseg * 4 + jj;
      float dx = cq0 - cjs[buf][jl][0];
      float dy = cq1 - cjs[buf][jl][1];
      float dz = cq2 - cjs[buf][jl][2];
      float d2 = dx * dx + dy * dy + dz * dz;
      float loc = __expf(-0.1f * d2);
      float e = fsq + cjs[buf][jl][3];
      e = (e > 0.f) ? e : 0.2f * e;
      float p = (loc > 0.01f) ? __expf(e * loc - Bq) : 0.f;
      lacc += p;
      unsigned short hb = f2bf(p);
      phi[buf][qA][jl] = hb;
      plo[buf][qA][jl] = f2bf(p - bf2f(hb));
    }
    __syncthreads();   // the ONLY barrier in the loop

    // ---- PV MFMA: 2 k-steps of 32 (A from phi[buf], B from hT) ----
    const int jc = j0 >> 4;
#pragma unroll
    for (int ks = 0; ks < 2; ks++) {
      short8 bfr[2];
#pragma unroll
      for (int f2 = 0; f2 < 2; f2++) {
        int col = (w * 2 + f2) * 16 + m;
        bfr[f2] = *(const short8*)&hTb[(size_t)(jc + ks * 2 + (quad >> 1)) * (FOUT_ * 16)
                                       + col * 16 + (quad & 1) * 8];
      }
      short8 ah = *(const short8*)&phi[buf][m][ks * 32 + quad * 8];
      short8 al = *(const short8*)&plo[buf][m][ks * 32 + quad * 8];
#pragma unroll
      for (int f2 = 0; f2 < 2; f2++) {
        acc[f2] = __builtin_amdgcn_mfma_f32_16x16x32_bf16(ah, bfr[f2], acc[f2], 0, 0, 0);
        acc[f2] = __builtin_amdgcn_mfma_f32_16x16x32_bf16(al, bfr[f2], acc[f2], 0, 0, 0);
      }
    }
  }

  // ---- denominator ----
  lred[jseg][qA] = lacc;
  __syncthreads();
  float dinv[4];
#pragma unroll
  for (int r = 0; r < 4; r++) {
    int q = quad * 4 + r;
    float s = 0.f;
#pragma unroll
    for (int k = 0; k < 16; k++) s += lred[k][q];
    dinv[r] = 1.0f / fmaxf(s, 1e-30f);
  }

  // ---- normalize, elu, store (D: row q = quad*4+r, col f = ftile*16+m) ----
#pragma unroll
  for (int f2 = 0; f2 < 2; f2++) {
    int f = (w * 2 + f2) * 16 + m;
#pragma unroll
    for (int r = 0; r < 4; r++) {
      int q = quad * 4 + r;
      float v = acc[f2][r] * dinv[r];
      v = (v > 0.f) ? v : expm1f(v);
      size_t oidx = ((size_t)(b * N_ + q0 + q)) * FOUT_ + f;
      if (isbf) ((unsigned short*)out)[oidx] = f2bf(v);
      else      ((float*)out)[oidx] = v;
    }
  }
}

extern "C" void kernel_launch(void* const* d_in, const int* in_sizes, int n_in,
                              void* d_out, int out_size, void* d_ws, size_t ws_size,
                              hipStream_t stream) {
  const void* x     = d_in[0];
  const void* coord = d_in[1];
  const void* W     = d_in[2];
  const void* a     = d_in[3];

  // ws layout: [64 floats flag/header][hT bf16][WThi][WTlo][fsrc][fdst][Mdst]
  int*            flag = (int*)d_ws;
  unsigned short* hT   = (unsigned short*)((float*)d_ws + 64);
  unsigned short* WThi = hT + (size_t)NROWS * FOUT_;
  unsigned short* WTlo = WThi + 128 * 256;
  float*          fsrc = (float*)(WTlo + 128 * 256);
  float*          fdst = fsrc + NROWS;
  float*          Mdst = fdst + NROWS;

  k_detect<<<1, 256, 0, stream>>>(x, flag);
  k_wt    <<<128, 256, 0, stream>>>(W, flag, WThi, WTlo);
  k_h     <<<NROWS / 64, 256, 0, stream>>>(x, WThi, WTlo, a, flag, hT, fsrc, fdst);
  k_mdst  <<<B_, 256, 0, stream>>>(fdst, Mdst);
  k_attn  <<<B_ * (N_ / 16), 256, 0, stream>>>(hT, coord, fsrc, fdst, Mdst, flag, d_out);
}